// Round 1
// baseline (98.071 us; speedup 1.0000x reference)
//
#include <hip/hip_runtime.h>

// BezierGlyph: 512x512 soft-distance field to 8 cubic Beziers (32 samples each).
// out[i,j] = 1 - sigmoid((W - softmin_dist(pixel, samples)) * 200)
// softmin via logsumexp with sharpness s = 256.

#define SIZE 512
#define NSAMP_TOT 256           // 8 strokes * 32 samples
#define RADIUS 0.06f            // pass-2 cutoff: exp(-256*0.06) ~ 2e-7, negligible

__device__ __forceinline__ float clamp01(float x) {
    return fminf(fmaxf(x, 0.0f), 1.0f);
}

__global__ __launch_bounds__(256) void bezier_glyph_kernel(
        const float* __restrict__ cp,   // (8,4,2) control points
        float* __restrict__ out)        // (512*512)
{
    __shared__ float2 smp[NSAMP_TOT];

    const int t = threadIdx.x;

    // ---- Stage 0: each thread computes one Bezier sample into LDS ----
    {
        const int s = t >> 5;          // stroke 0..7
        const int j = t & 31;          // sample 0..31
        const float* p = cp + s * 8;
        const float x0 = clamp01(p[0]), y0 = clamp01(p[1]);
        const float x1 = clamp01(p[2]), y1 = clamp01(p[3]);
        const float x2 = clamp01(p[4]), y2 = clamp01(p[5]);
        const float x3 = clamp01(p[6]), y3 = clamp01(p[7]);
        const float tt = (float)j * (1.0f / 31.0f);
        const float mt = 1.0f - tt;
        const float w0 = mt * mt * mt;
        const float w1 = 3.0f * mt * mt * tt;
        const float w2 = 3.0f * mt * tt * tt;
        const float w3 = tt * tt * tt;
        smp[t] = make_float2(w0 * x0 + w1 * x1 + w2 * x2 + w3 * x3,
                             w0 * y0 + w1 * y1 + w2 * y2 + w3 * y3);
    }
    __syncthreads();

    // ---- Pixel assignment: block = 32x32 tile, thread = 1 row x 4 cols ----
    const int b = blockIdx.x;
    const int row = ((b >> 4) << 5) + (t >> 3);          // global row
    const int col = ((b & 15) << 5) + ((t & 7) << 2);    // global col (x4)
    const float inv = 1.0f / 511.0f;
    const float py  = (float)row * inv;
    const float px0 = (float)(col + 0) * inv;
    const float px1 = (float)(col + 1) * inv;
    const float px2 = (float)(col + 2) * inv;
    const float px3 = (float)(col + 3) * inv;

    // ---- Pass 1: min squared distance (sqrt-free; sqrt is monotone) ----
    float m0 = 3e38f, m1 = 3e38f, m2 = 3e38f, m3 = 3e38f;
    #pragma unroll 8
    for (int k = 0; k < NSAMP_TOT; ++k) {
        const float2 sp = smp[k];
        const float dy  = py - sp.y;
        const float dy2 = dy * dy;
        const float dx0 = px0 - sp.x;
        const float dx1 = px1 - sp.x;
        const float dx2 = px2 - sp.x;
        const float dx3 = px3 - sp.x;
        m0 = fminf(m0, fmaf(dx0, dx0, dy2));
        m1 = fminf(m1, fmaf(dx1, dx1, dy2));
        m2 = fminf(m2, fmaf(dx2, dx2, dy2));
        m3 = fminf(m3, fmaf(dx3, dx3, dy2));
    }
    const float d0 = __builtin_amdgcn_sqrtf(m0);
    const float d1 = __builtin_amdgcn_sqrtf(m1);
    const float d2 = __builtin_amdgcn_sqrtf(m2);
    const float d3 = __builtin_amdgcn_sqrtf(m3);

    // squared-distance thresholds for negligible-term skipping
    const float t0 = (d0 + RADIUS) * (d0 + RADIUS);
    const float t1 = (d1 + RADIUS) * (d1 + RADIUS);
    const float t2 = (d2 + RADIUS) * (d2 + RADIUS);
    const float t3 = (d3 + RADIUS) * (d3 + RADIUS);

    // ---- Pass 2: S = sum_k exp(-s*(d_k - dmin)), s = 256 ----
    // exp(x) = exp2(x * log2(e)); C = 256 * log2(e)
    const float C = 369.3299304675766f;
    float S0 = 0.0f, S1 = 0.0f, S2 = 0.0f, S3 = 0.0f;
    #pragma unroll 4
    for (int k = 0; k < NSAMP_TOT; ++k) {
        const float2 sp = smp[k];
        const float dy  = py - sp.y;
        const float dy2 = dy * dy;
        const float dx0 = px0 - sp.x;
        const float dx1 = px1 - sp.x;
        const float dx2 = px2 - sp.x;
        const float dx3 = px3 - sp.x;
        const float q0 = fmaf(dx0, dx0, dy2);
        const float q1 = fmaf(dx1, dx1, dy2);
        const float q2 = fmaf(dx2, dx2, dy2);
        const float q3 = fmaf(dx3, dx3, dy2);
        // whole-wave skip when every lane's 4 pixels are far from this sample
        if ((q0 < t0) | (q1 < t1) | (q2 < t2) | (q3 < t3)) {
            S0 += __builtin_amdgcn_exp2f(C * (d0 - __builtin_amdgcn_sqrtf(q0)));
            S1 += __builtin_amdgcn_exp2f(C * (d1 - __builtin_amdgcn_sqrtf(q1)));
            S2 += __builtin_amdgcn_exp2f(C * (d2 - __builtin_amdgcn_sqrtf(q2)));
            S3 += __builtin_amdgcn_exp2f(C * (d3 - __builtin_amdgcn_sqrtf(q3)));
        }
    }

    // min_dist = dmin - log(S)/s = dmin - log2(S)/C        (S >= 1 always)
    const float md0 = d0 - __builtin_amdgcn_logf(S0) * (1.0f / C);
    const float md1 = d1 - __builtin_amdgcn_logf(S1) * (1.0f / C);
    const float md2 = d2 - __builtin_amdgcn_logf(S2) * (1.0f / C);
    const float md3 = d3 - __builtin_amdgcn_logf(S3) * (1.0f / C);

    // out = 1 - sigmoid((W - md)*200) = 1 / (1 + exp((W - md)*200))
    const float L2E = 1.4426950408889634f;
    const float z0 = (0.04f - md0) * 200.0f * L2E;
    const float z1 = (0.04f - md1) * 200.0f * L2E;
    const float z2 = (0.04f - md2) * 200.0f * L2E;
    const float z3 = (0.04f - md3) * 200.0f * L2E;
    float4 o;
    o.x = __builtin_amdgcn_rcpf(1.0f + __builtin_amdgcn_exp2f(z0));
    o.y = __builtin_amdgcn_rcpf(1.0f + __builtin_amdgcn_exp2f(z1));
    o.z = __builtin_amdgcn_rcpf(1.0f + __builtin_amdgcn_exp2f(z2));
    o.w = __builtin_amdgcn_rcpf(1.0f + __builtin_amdgcn_exp2f(z3));

    *reinterpret_cast<float4*>(&out[row * SIZE + col]) = o;
}

extern "C" void kernel_launch(void* const* d_in, const int* in_sizes, int n_in,
                              void* d_out, int out_size, void* d_ws, size_t ws_size,
                              hipStream_t stream) {
    const float* cp = (const float*)d_in[0];   // control_points (8,4,2)
    // d_in[1] = pixel_grid — recomputed analytically in-kernel (i/511)
    float* out = (float*)d_out;
    // 512x512 pixels, 32x32 tile per block, 4 px/thread -> 256 blocks x 256 thr
    bezier_glyph_kernel<<<dim3(256), dim3(256), 0, stream>>>(cp, out);
}

// Round 2
// 73.595 us; speedup vs baseline: 1.3326x; 1.3326x over previous
//
#include <hip/hip_runtime.h>

// BezierGlyph: 512x512 soft-distance field to 8 cubic Beziers (32 samples each).
// out = 1 - sigmoid((W - softmin_dist)*200), softmin = -logsumexp(-256*d)/256.
//
// Structure (R2): 256 blocks x 1024 threads. Each block owns a 32x32 pixel
// tile; 4 sub-groups of 256 threads each cover the SAME pixels (4 px/thread,
// row of 4) but a disjoint 64-sample slice. Block-level min-reduce between
// pass 1 (min d^2) and pass 2 (sum of exp), sum-reduce at the end.
// -> 16 waves/CU (vs 4 in R1) to hide LDS/dependency latency.

#define SIZE 512
#define NSAMP 256
#define RADIUS 0.06f        // pass-2 term cutoff: exp(-256*0.06) ~ 2e-7
#define FARCUT 0.122f       // 0.04 + ln(256)/256 + 0.06: beyond this out==1 (+-6e-6)

__device__ __forceinline__ float clamp01(float x) {
    return fminf(fmaxf(x, 0.0f), 1.0f);
}

__global__ __launch_bounds__(1024) void bezier_glyph_kernel(
        const float* __restrict__ cp,   // (8,4,2) control points
        float* __restrict__ out)        // (512*512)
{
    __shared__ float2 smp[NSAMP];        // 2 KB
    __shared__ float  redM[4][4][256];   // 16 KB  min-reduce (sub, px, tt) SoA
    __shared__ float  redS[4][4][256];   // 16 KB  sum-reduce

    const int tid = threadIdx.x;
    const int sub = tid >> 8;            // sample-slice 0..3
    const int tt  = tid & 255;           // pixel-thread 0..255

    // ---- Stage 0: threads 0..255 compute one Bezier sample each ----
    if (tid < NSAMP) {
        const int s = tid >> 5;          // stroke 0..7
        const int j = tid & 31;          // sample 0..31
        const float* p = cp + s * 8;
        const float x0 = clamp01(p[0]), y0 = clamp01(p[1]);
        const float x1 = clamp01(p[2]), y1 = clamp01(p[3]);
        const float x2 = clamp01(p[4]), y2 = clamp01(p[5]);
        const float x3 = clamp01(p[6]), y3 = clamp01(p[7]);
        const float u  = (float)j * (1.0f / 31.0f);
        const float mu = 1.0f - u;
        const float w0 = mu * mu * mu;
        const float w1 = 3.0f * mu * mu * u;
        const float w2 = 3.0f * mu * u * u;
        const float w3 = u * u * u;
        smp[tid] = make_float2(w0 * x0 + w1 * x1 + w2 * x2 + w3 * x3,
                               w0 * y0 + w1 * y1 + w2 * y2 + w3 * y3);
    }
    __syncthreads();

    // ---- Pixel assignment: 32x32 tile, thread = 1 row x 4 cols ----
    const int b   = blockIdx.x;
    const int row = ((b >> 4) << 5) + (tt >> 3);
    const int col = ((b & 15) << 5) + ((tt & 7) << 2);
    const float inv = 1.0f / 511.0f;
    const float py  = (float)row * inv;
    const float px0 = (float)(col + 0) * inv;
    const float px1 = (float)(col + 1) * inv;
    const float px2 = (float)(col + 2) * inv;
    const float px3 = (float)(col + 3) * inv;

    const float4* smp4 = reinterpret_cast<const float4*>(smp);
    const int kbase = sub << 5;          // float4 index: sub*64 samples / 2

    // ---- Pass 1: min d^2 over this sub's 64 samples (2 samples/iter) ----
    float m0 = 3e38f, m1 = 3e38f, m2 = 3e38f, m3 = 3e38f;
    #pragma unroll 8
    for (int kk = 0; kk < 32; ++kk) {
        const float4 sp = smp4[kbase + kk];     // (xA,yA,xB,yB)
        const float dyA = py - sp.y, dyB = py - sp.w;
        const float dyA2 = dyA * dyA, dyB2 = dyB * dyB;
        float dx;
        dx = px0 - sp.x; const float q0A = fmaf(dx, dx, dyA2);
        dx = px0 - sp.z; const float q0B = fmaf(dx, dx, dyB2);
        dx = px1 - sp.x; const float q1A = fmaf(dx, dx, dyA2);
        dx = px1 - sp.z; const float q1B = fmaf(dx, dx, dyB2);
        dx = px2 - sp.x; const float q2A = fmaf(dx, dx, dyA2);
        dx = px2 - sp.z; const float q2B = fmaf(dx, dx, dyB2);
        dx = px3 - sp.x; const float q3A = fmaf(dx, dx, dyA2);
        dx = px3 - sp.z; const float q3B = fmaf(dx, dx, dyB2);
        m0 = fminf(m0, fminf(q0A, q0B));        // -> v_min3_f32
        m1 = fminf(m1, fminf(q1A, q1B));
        m2 = fminf(m2, fminf(q2A, q2B));
        m3 = fminf(m3, fminf(q3A, q3B));
    }
    redM[sub][0][tt] = m0;
    redM[sub][1][tt] = m1;
    redM[sub][2][tt] = m2;
    redM[sub][3][tt] = m3;
    __syncthreads();

    // global (all-256-sample) min d^2 per pixel, known to all 4 subs
    m0 = fminf(fminf(redM[0][0][tt], redM[1][0][tt]), fminf(redM[2][0][tt], redM[3][0][tt]));
    m1 = fminf(fminf(redM[0][1][tt], redM[1][1][tt]), fminf(redM[2][1][tt], redM[3][1][tt]));
    m2 = fminf(fminf(redM[0][2][tt], redM[1][2][tt]), fminf(redM[2][2][tt], redM[3][2][tt]));
    m3 = fminf(fminf(redM[0][3][tt], redM[1][3][tt]), fminf(redM[2][3][tt], redM[3][3][tt]));

    const float d0 = __builtin_amdgcn_sqrtf(m0);
    const float d1 = __builtin_amdgcn_sqrtf(m1);
    const float d2 = __builtin_amdgcn_sqrtf(m2);
    const float d3 = __builtin_amdgcn_sqrtf(m3);

    // ---- Pass 2: S = sum exp(-256*(d_k - dmin)) over this sub's samples ----
    const float C  = 369.3299304675766f;   // 256 * log2(e)
    const float nC = -C;
    float S0 = 0.0f, S1 = 0.0f, S2 = 0.0f, S3 = 0.0f;

    // far-pixel skip: if all 4 px have dmin > FARCUT, out==1 to 6e-6; S=0
    // falls through log(0) = -inf -> md = +inf -> out = 1 exactly.
    if (fminf(fminf(d0, d1), fminf(d2, d3)) < FARCUT) {
        const float t0 = (d0 + RADIUS) * (d0 + RADIUS);
        const float t1 = (d1 + RADIUS) * (d1 + RADIUS);
        const float t2 = (d2 + RADIUS) * (d2 + RADIUS);
        const float t3 = (d3 + RADIUS) * (d3 + RADIUS);
        const float cd0 = C * d0, cd1 = C * d1, cd2 = C * d2, cd3 = C * d3;
        #pragma unroll 4
        for (int kk = 0; kk < 32; ++kk) {
            const float4 sp = smp4[kbase + kk];
            const float dyA = py - sp.y, dyB = py - sp.w;
            const float dyA2 = dyA * dyA, dyB2 = dyB * dyB;
            float dx;
            dx = px0 - sp.x; const float q0A = fmaf(dx, dx, dyA2);
            dx = px0 - sp.z; const float q0B = fmaf(dx, dx, dyB2);
            dx = px1 - sp.x; const float q1A = fmaf(dx, dx, dyA2);
            dx = px1 - sp.z; const float q1B = fmaf(dx, dx, dyB2);
            dx = px2 - sp.x; const float q2A = fmaf(dx, dx, dyA2);
            dx = px2 - sp.z; const float q2B = fmaf(dx, dx, dyB2);
            dx = px3 - sp.x; const float q3A = fmaf(dx, dx, dyA2);
            dx = px3 - sp.z; const float q3B = fmaf(dx, dx, dyB2);
            const bool any = (q0A < t0) | (q0B < t0) | (q1A < t1) | (q1B < t1)
                           | (q2A < t2) | (q2B < t2) | (q3A < t3) | (q3B < t3);
            if (any) {
                S0 += __builtin_amdgcn_exp2f(fmaf(nC, __builtin_amdgcn_sqrtf(q0A), cd0))
                    + __builtin_amdgcn_exp2f(fmaf(nC, __builtin_amdgcn_sqrtf(q0B), cd0));
                S1 += __builtin_amdgcn_exp2f(fmaf(nC, __builtin_amdgcn_sqrtf(q1A), cd1))
                    + __builtin_amdgcn_exp2f(fmaf(nC, __builtin_amdgcn_sqrtf(q1B), cd1));
                S2 += __builtin_amdgcn_exp2f(fmaf(nC, __builtin_amdgcn_sqrtf(q2A), cd2))
                    + __builtin_amdgcn_exp2f(fmaf(nC, __builtin_amdgcn_sqrtf(q2B), cd2));
                S3 += __builtin_amdgcn_exp2f(fmaf(nC, __builtin_amdgcn_sqrtf(q3A), cd3))
                    + __builtin_amdgcn_exp2f(fmaf(nC, __builtin_amdgcn_sqrtf(q3B), cd3));
            }
        }
    }
    redS[sub][0][tt] = S0;
    redS[sub][1][tt] = S1;
    redS[sub][2][tt] = S2;
    redS[sub][3][tt] = S3;
    __syncthreads();

    // ---- Epilogue: sub 0 sums partials and writes 4 pixels ----
    if (sub == 0) {
        const float St0 = redS[0][0][tt] + redS[1][0][tt] + redS[2][0][tt] + redS[3][0][tt];
        const float St1 = redS[0][1][tt] + redS[1][1][tt] + redS[2][1][tt] + redS[3][1][tt];
        const float St2 = redS[0][2][tt] + redS[1][2][tt] + redS[2][2][tt] + redS[3][2][tt];
        const float St3 = redS[0][3][tt] + redS[1][3][tt] + redS[2][3][tt] + redS[3][3][tt];

        // min_dist = dmin - log2(S)/C ; out = 1/(1 + exp2((W-md)*200*log2e))
        const float md0 = d0 - __builtin_amdgcn_logf(St0) * (1.0f / C);
        const float md1 = d1 - __builtin_amdgcn_logf(St1) * (1.0f / C);
        const float md2 = d2 - __builtin_amdgcn_logf(St2) * (1.0f / C);
        const float md3 = d3 - __builtin_amdgcn_logf(St3) * (1.0f / C);

        const float K = 200.0f * 1.4426950408889634f;
        float4 o;
        o.x = __builtin_amdgcn_rcpf(1.0f + __builtin_amdgcn_exp2f((0.04f - md0) * K));
        o.y = __builtin_amdgcn_rcpf(1.0f + __builtin_amdgcn_exp2f((0.04f - md1) * K));
        o.z = __builtin_amdgcn_rcpf(1.0f + __builtin_amdgcn_exp2f((0.04f - md2) * K));
        o.w = __builtin_amdgcn_rcpf(1.0f + __builtin_amdgcn_exp2f((0.04f - md3) * K));

        *reinterpret_cast<float4*>(&out[row * SIZE + col]) = o;
    }
}

extern "C" void kernel_launch(void* const* d_in, const int* in_sizes, int n_in,
                              void* d_out, int out_size, void* d_ws, size_t ws_size,
                              hipStream_t stream) {
    const float* cp = (const float*)d_in[0];   // control_points (8,4,2)
    float* out = (float*)d_out;                // pixel_grid recomputed in-kernel
    bezier_glyph_kernel<<<dim3(256), dim3(1024), 0, stream>>>(cp, out);
}

// Round 3
// 60.497 us; speedup vs baseline: 1.6211x; 1.2165x over previous
//
#include <hip/hip_runtime.h>

// BezierGlyph R3: per-tile sample culling.
// 1024 blocks x 256 threads; block = 16x16 pixel tile, thread = 1 pixel.
// Stage 0: thread t computes Bezier sample t (256 total) + its distance to
//   tile center (dc) and squared distance to tile bbox (bb2).
// List 1 (exact-min superset): keep sample iff dc <= min(Dc, FARCUT+HD)+2*HD.
//   Lemma: if a pixel's min over list1 is < FARCUT it equals the true min;
//   else true min is also > FARCUT and out==1 within 7e-8.
// List 2 (logsumexp superset): keep iff dist(bbox) <= max_px(min(d,FARCUT))
//   + RADIUS; dropped terms are each < exp(-256*0.06) ~ 2e-7.
// Far tiles: n1 == 0 -> all pixels out = 1.0, early exit.

#define SIZE 512
#define RADIUS 0.06f
#define FARCUT 0.1217f          // 0.04 + ln(256)/256 + RADIUS
#define HB 0.01467710f          // 7.5/511        (tile bbox half-extent)
#define HD 0.02075670f          // 7.5*sqrt(2)/511 (pixel-to-center max dist)

__device__ __forceinline__ float clamp01(float x) {
    return fminf(fmaxf(x, 0.0f), 1.0f);
}
__device__ __forceinline__ float wave_min(float v) {
    #pragma unroll
    for (int m = 1; m < 64; m <<= 1) v = fminf(v, __shfl_xor(v, m));
    return v;
}
__device__ __forceinline__ float wave_max(float v) {
    #pragma unroll
    for (int m = 1; m < 64; m <<= 1) v = fmaxf(v, __shfl_xor(v, m));
    return v;
}

__global__ __launch_bounds__(256) void bezier_glyph_kernel(
        const float* __restrict__ cp,   // (8,4,2) control points
        float* __restrict__ out)        // (512*512)
{
    __shared__ float2 list1[260];
    __shared__ float2 list2[260];
    __shared__ float  redbuf[8];
    __shared__ int    n1s, n2s;

    const int tid  = threadIdx.x;
    const int lane = tid & 63;
    const int wid  = tid >> 6;
    if (tid == 0) { n1s = 0; n2s = 0; }

    // ---- tile geometry ----
    const int b        = blockIdx.x;
    const int row_base = (b >> 5) << 4;
    const int col_base = (b & 31) << 4;
    const float inv = 1.0f / 511.0f;
    const float cx  = ((float)col_base + 7.5f) * inv;
    const float cy  = ((float)row_base + 7.5f) * inv;

    // ---- Stage 0: thread t computes Bezier sample t ----
    float sx, sy, dc, bb2;
    {
        const int s = tid >> 5, j = tid & 31;
        const float* p = cp + s * 8;
        const float x0 = clamp01(p[0]), y0 = clamp01(p[1]);
        const float x1 = clamp01(p[2]), y1 = clamp01(p[3]);
        const float x2 = clamp01(p[4]), y2 = clamp01(p[5]);
        const float x3 = clamp01(p[6]), y3 = clamp01(p[7]);
        const float u  = (float)j * (1.0f / 31.0f);
        const float mu = 1.0f - u;
        const float w0 = mu * mu * mu;
        const float w1 = 3.0f * mu * mu * u;
        const float w2 = 3.0f * mu * u * u;
        const float w3 = u * u * u;
        sx = w0 * x0 + w1 * x1 + w2 * x2 + w3 * x3;
        sy = w0 * y0 + w1 * y1 + w2 * y2 + w3 * y3;
        const float dcx = sx - cx, dcy = sy - cy;
        dc = __builtin_amdgcn_sqrtf(dcx * dcx + dcy * dcy);
        const float bx = fmaxf(fabsf(dcx) - HB, 0.0f);
        const float by = fmaxf(fabsf(dcy) - HB, 0.0f);
        bb2 = bx * bx + by * by;
    }

    // ---- block-min of center distance ----
    {
        const float wm = wave_min(dc);
        if (lane == 0) redbuf[wid] = wm;
    }
    __syncthreads();                                              // sync 1
    const float Dc = fminf(fminf(redbuf[0], redbuf[1]),
                           fminf(redbuf[2], redbuf[3]));
    const float T1 = fminf(Dc, FARCUT + HD) + 2.0f * HD + 1e-4f;

    // ---- build list1 (ballot-compacted append) ----
    {
        const bool keep = (dc <= T1);
        const unsigned long long mk = __ballot(keep);
        int base = 0;
        if (lane == 0) base = atomicAdd(&n1s, (int)__popcll(mk));
        base = __shfl(base, 0);
        if (keep) {
            const int pos = base + (int)__popcll(mk & ((1ull << lane) - 1ull));
            list1[pos] = make_float2(sx, sy);
        }
    }
    __syncthreads();                                              // sync 2
    const int n1 = n1s;
    if (tid < 4) list1[n1 + tid] = make_float2(1e3f, 1e3f);       // pad
    __syncthreads();                                              // sync 3

    // ---- pixel ----
    const int row = row_base + (tid >> 4);
    const int col = col_base + (tid & 15);
    const float py = (float)row * inv;
    const float px = (float)col * inv;

    // ---- Pass 1: min d^2 over list1 ----
    float m = 3e38f;
    const int n1r = (n1 + 3) & ~3;
    for (int k = 0; k < n1r; k += 4) {
        const float2 a = list1[k],     b2 = list1[k + 1];
        const float2 c = list1[k + 2], e  = list1[k + 3];
        float dx, dy;
        dx = px - a.x;  dy = py - a.y;  const float qa = fmaf(dx, dx, dy * dy);
        dx = px - b2.x; dy = py - b2.y; const float qb = fmaf(dx, dx, dy * dy);
        dx = px - c.x;  dy = py - c.y;  const float qc = fmaf(dx, dx, dy * dy);
        dx = px - e.x;  dy = py - e.y;  const float qe = fmaf(dx, dx, dy * dy);
        m = fminf(m, fminf(fminf(qa, qb), fminf(qc, qe)));
    }
    const float d   = __builtin_amdgcn_sqrtf(m);
    const float cap = fminf(d, FARCUT);

    // ---- block reduces: min(d) for far-tile exit, max(cap) for list2 ----
    {
        const float wdm = wave_min(d);
        const float wcm = wave_max(cap);
        if (lane == 0) { redbuf[wid] = wdm; redbuf[4 + wid] = wcm; }
    }
    __syncthreads();                                              // sync 4
    const float dminblk = fminf(fminf(redbuf[0], redbuf[1]),
                                fminf(redbuf[2], redbuf[3]));
    const float Tmax    = fmaxf(fmaxf(redbuf[4], redbuf[5]),
                                fmaxf(redbuf[6], redbuf[7]));

    if (dminblk > FARCUT) {            // whole tile far: out == 1 (+-6e-6)
        out[row * SIZE + col] = 1.0f;
        return;
    }

    // ---- build list2 ----
    {
        const float T2 = Tmax + RADIUS + 1e-4f;
        const bool keep = (bb2 <= T2 * T2);
        const unsigned long long mk = __ballot(keep);
        int base = 0;
        if (lane == 0) base = atomicAdd(&n2s, (int)__popcll(mk));
        base = __shfl(base, 0);
        if (keep) {
            const int pos = base + (int)__popcll(mk & ((1ull << lane) - 1ull));
            list2[pos] = make_float2(sx, sy);
        }
    }
    __syncthreads();                                              // sync 5
    const int n2 = n2s;
    if (tid < 4) list2[n2 + tid] = make_float2(1e3f, 1e3f);       // pad -> exp2(-huge)=0
    __syncthreads();                                              // sync 6

    // ---- Pass 2: S = sum exp2(C*(d - d_k)) over list2 ----
    const float C  = 369.3299304675766f;   // 256 * log2(e)
    const float nC = -C;
    const float cd = C * d;
    float S = 0.0f;
    const int n2r = (n2 + 3) & ~3;
    for (int k = 0; k < n2r; k += 4) {
        const float2 a = list2[k],     b2 = list2[k + 1];
        const float2 c = list2[k + 2], e  = list2[k + 3];
        float dx, dy;
        dx = px - a.x;  dy = py - a.y;  const float qa = fmaf(dx, dx, dy * dy);
        dx = px - b2.x; dy = py - b2.y; const float qb = fmaf(dx, dx, dy * dy);
        dx = px - c.x;  dy = py - c.y;  const float qc = fmaf(dx, dx, dy * dy);
        dx = px - e.x;  dy = py - e.y;  const float qe = fmaf(dx, dx, dy * dy);
        S += __builtin_amdgcn_exp2f(fmaf(nC, __builtin_amdgcn_sqrtf(qa), cd))
           + __builtin_amdgcn_exp2f(fmaf(nC, __builtin_amdgcn_sqrtf(qb), cd))
           + __builtin_amdgcn_exp2f(fmaf(nC, __builtin_amdgcn_sqrtf(qc), cd))
           + __builtin_amdgcn_exp2f(fmaf(nC, __builtin_amdgcn_sqrtf(qe), cd));
    }

    // md = d - log2(S)/C ; S==0 -> log=-inf -> md=+inf -> out=1 (correct: d>FARCUT)
    const float md = d - __builtin_amdgcn_logf(S) * (1.0f / C);
    const float K  = 288.53900817779268f;  // 200 * log2(e)
    const float o  = __builtin_amdgcn_rcpf(
                        1.0f + __builtin_amdgcn_exp2f((0.04f - md) * K));
    out[row * SIZE + col] = o;
}

extern "C" void kernel_launch(void* const* d_in, const int* in_sizes, int n_in,
                              void* d_out, int out_size, void* d_ws, size_t ws_size,
                              hipStream_t stream) {
    const float* cp = (const float*)d_in[0];   // control_points (8,4,2)
    float* out = (float*)d_out;                // pixel_grid recomputed in-kernel
    bezier_glyph_kernel<<<dim3(1024), dim3(256), 0, stream>>>(cp, out);
}

// Round 4
// 59.369 us; speedup vs baseline: 1.6519x; 1.0190x over previous
//
#include <hip/hip_runtime.h>

// BezierGlyph R4: single-wave blocks, 8x8 tiles.
// 4096 blocks x 64 threads; block = one wave = one 8x8 pixel tile.
// Stage 0: thread t evaluates Bezier samples 4t..4t+3 (same stroke).
// List 1 (exact-min superset): dc <= min(Dc, FARCUT+HD) + 2*HD.
//   If a pixel's min over list1 < FARCUT it is the true min; else both
//   true and computed saturate to out==1 (+-1e-7).
// List 2 (logsumexp superset): dist(bbox) <= max_px(min(d,FARCUT)) + RADIUS;
//   dropped terms each < exp(-256*0.06) ~ 2e-7 (<=255 of them -> md err <1e-6).
// Wave-wide ballot compaction (no atomics), shfl reductions (no LDS barriers).

#define SIZE 512
#define RADIUS 0.06f
#define FARCUT 0.1217f          // 0.04 + ln(256)/256 + RADIUS
#define HB 0.00684932f          // 3.5/511        (tile bbox half-extent)
#define HD 0.00968631f          // 3.5*sqrt(2)/511 (pixel-to-center max dist)

__device__ __forceinline__ float clamp01(float x) {
    return fminf(fmaxf(x, 0.0f), 1.0f);
}
__device__ __forceinline__ float wave_min(float v) {
    #pragma unroll
    for (int m = 1; m < 64; m <<= 1) v = fminf(v, __shfl_xor(v, m));
    return v;
}
__device__ __forceinline__ float wave_max(float v) {
    #pragma unroll
    for (int m = 1; m < 64; m <<= 1) v = fmaxf(v, __shfl_xor(v, m));
    return v;
}

__global__ __launch_bounds__(64) void bezier_glyph_kernel(
        const float* __restrict__ cp,   // (8,4,2) control points
        float* __restrict__ out)        // (512*512)
{
    __shared__ float2 list1[260];
    __shared__ float2 list2[260];

    const int tid = threadIdx.x;        // == lane (single wave)
    const int b   = blockIdx.x;
    const int row_base = (b >> 6) << 3;
    const int col_base = (b & 63) << 3;
    const float inv = 1.0f / 511.0f;
    const float cx  = ((float)col_base + 3.5f) * inv;
    const float cy  = ((float)row_base + 3.5f) * inv;

    // ---- Stage 0: thread t evaluates samples 4t..4t+3 (one stroke) ----
    float sxv[4], syv[4], dc2v[4], bb2v[4];
    {
        const int s = tid >> 3;                 // stroke of samples 4t..4t+3
        const float* p = cp + s * 8;
        const float x0 = clamp01(p[0]), y0 = clamp01(p[1]);
        const float x1 = clamp01(p[2]), y1 = clamp01(p[3]);
        const float x2 = clamp01(p[4]), y2 = clamp01(p[5]);
        const float x3 = clamp01(p[6]), y3 = clamp01(p[7]);
        #pragma unroll
        for (int r = 0; r < 4; ++r) {
            const int j    = ((tid << 2) + r) & 31;
            const float u  = (float)j * (1.0f / 31.0f);
            const float mu = 1.0f - u;
            const float w0 = mu * mu * mu;
            const float w1 = 3.0f * mu * mu * u;
            const float w2 = 3.0f * mu * u * u;
            const float w3 = u * u * u;
            const float sx = w0 * x0 + w1 * x1 + w2 * x2 + w3 * x3;
            const float sy = w0 * y0 + w1 * y1 + w2 * y2 + w3 * y3;
            sxv[r] = sx; syv[r] = sy;
            const float dcx = sx - cx, dcy = sy - cy;
            dc2v[r] = dcx * dcx + dcy * dcy;
            const float bx = fmaxf(fabsf(dcx) - HB, 0.0f);
            const float by = fmaxf(fabsf(dcy) - HB, 0.0f);
            bb2v[r] = bx * bx + by * by;
        }
    }

    // ---- wave-min of center distance^2, one sqrt ----
    const float Dc = __builtin_amdgcn_sqrtf(wave_min(
        fminf(fminf(dc2v[0], dc2v[1]), fminf(dc2v[2], dc2v[3]))));
    const float T1  = fminf(Dc, FARCUT + HD) + 2.0f * HD + 1e-4f;
    const float T1s = T1 * T1;

    // ---- build list1: 4 ballot-compaction rounds, no atomics ----
    const unsigned long long lt = (tid == 63) ? ~0ull >> 1
                                              : (1ull << tid) - 1ull;
    int n1 = 0;
    #pragma unroll
    for (int r = 0; r < 4; ++r) {
        const bool keep = (dc2v[r] <= T1s);
        const unsigned long long mk = __ballot(keep);
        if (keep)
            list1[n1 + (int)__popcll(mk & lt)] = make_float2(sxv[r], syv[r]);
        n1 += (int)__popcll(mk);
    }

    const int row = row_base + (tid >> 3);
    const int col = col_base + (tid & 7);

    if (n1 == 0) {                      // whole tile far: out == 1 (+-1e-7)
        out[row * SIZE + col] = 1.0f;
        return;
    }
    if (tid < 4) list1[n1 + tid] = make_float2(1e3f, 1e3f);   // pad
    __syncthreads();                    // single wave: just lgkmcnt drain

    const float py = (float)row * inv;
    const float px = (float)col * inv;

    // ---- Pass 1: min d^2 over list1 ----
    float m = 3e38f;
    const int n1r = (n1 + 3) & ~3;
    for (int k = 0; k < n1r; k += 4) {
        const float2 a = list1[k],     b2 = list1[k + 1];
        const float2 c = list1[k + 2], e  = list1[k + 3];
        float dx, dy;
        dx = px - a.x;  dy = py - a.y;  const float qa = fmaf(dx, dx, dy * dy);
        dx = px - b2.x; dy = py - b2.y; const float qb = fmaf(dx, dx, dy * dy);
        dx = px - c.x;  dy = py - c.y;  const float qc = fmaf(dx, dx, dy * dy);
        dx = px - e.x;  dy = py - e.y;  const float qe = fmaf(dx, dx, dy * dy);
        m = fminf(m, fminf(fminf(qa, qb), fminf(qc, qe)));
    }
    const float d   = __builtin_amdgcn_sqrtf(m);
    const float cap = fminf(d, FARCUT);

    const float dminw = wave_min(d);
    const float Tmax  = wave_max(cap);

    if (dminw > FARCUT) {               // all 64 px far: out == 1 (+-1e-7)
        out[row * SIZE + col] = 1.0f;
        return;
    }

    // ---- build list2 ----
    const float T2  = Tmax + RADIUS + 1e-4f;
    const float T2s = T2 * T2;
    int n2 = 0;
    #pragma unroll
    for (int r = 0; r < 4; ++r) {
        const bool keep = (bb2v[r] <= T2s);
        const unsigned long long mk = __ballot(keep);
        if (keep)
            list2[n2 + (int)__popcll(mk & lt)] = make_float2(sxv[r], syv[r]);
        n2 += (int)__popcll(mk);
    }
    if (tid < 4) list2[n2 + tid] = make_float2(1e3f, 1e3f);   // pad -> exp2 -> 0
    __syncthreads();

    // ---- Pass 2: S = sum exp2(C*(d - d_k)) over list2 ----
    const float C  = 369.3299304675766f;   // 256 * log2(e)
    const float nC = -C;
    const float cd = C * d;
    float S = 0.0f;
    const int n2r = (n2 + 3) & ~3;
    for (int k = 0; k < n2r; k += 4) {
        const float2 a = list2[k],     b2 = list2[k + 1];
        const float2 c = list2[k + 2], e  = list2[k + 3];
        float dx, dy;
        dx = px - a.x;  dy = py - a.y;  const float qa = fmaf(dx, dx, dy * dy);
        dx = px - b2.x; dy = py - b2.y; const float qb = fmaf(dx, dx, dy * dy);
        dx = px - c.x;  dy = py - c.y;  const float qc = fmaf(dx, dx, dy * dy);
        dx = px - e.x;  dy = py - e.y;  const float qe = fmaf(dx, dx, dy * dy);
        S += __builtin_amdgcn_exp2f(fmaf(nC, __builtin_amdgcn_sqrtf(qa), cd))
           + __builtin_amdgcn_exp2f(fmaf(nC, __builtin_amdgcn_sqrtf(qb), cd))
           + __builtin_amdgcn_exp2f(fmaf(nC, __builtin_amdgcn_sqrtf(qc), cd))
           + __builtin_amdgcn_exp2f(fmaf(nC, __builtin_amdgcn_sqrtf(qe), cd));
    }

    // md = d - log2(S)/C ; S==0 -> log = -inf -> md = +inf -> out = 1 (d > FARCUT)
    const float md = d - __builtin_amdgcn_logf(S) * (1.0f / C);
    const float K  = 288.53900817779268f;  // 200 * log2(e)
    out[row * SIZE + col] = __builtin_amdgcn_rcpf(
        1.0f + __builtin_amdgcn_exp2f((0.04f - md) * K));
}

extern "C" void kernel_launch(void* const* d_in, const int* in_sizes, int n_in,
                              void* d_out, int out_size, void* d_ws, size_t ws_size,
                              hipStream_t stream) {
    const float* cp = (const float*)d_in[0];   // control_points (8,4,2)
    float* out = (float*)d_out;                // pixel_grid recomputed in-kernel
    bezier_glyph_kernel<<<dim3(4096), dim3(64), 0, stream>>>(cp, out);
}

// Round 5
// 58.491 us; speedup vs baseline: 1.6767x; 1.0150x over previous
//
#include <hip/hip_runtime.h>

// BezierGlyph R5: single fused anchored-logsumexp pass, single-wave 8x8 tiles.
// 4096 blocks x 64 threads; block = one wave = one 8x8 pixel tile.
//
// Anchor identity: for wave-uniform A <= min_k d_k (all pixels/samples),
//   md = A - log2( sum_k exp2(C*(A - d_k)) ) / C       (C = 256*log2 e)
// is EXACT logsumexp — no per-pixel min pass required. We take
//   A = sqrt( min_samples bb2 ),  bb2 = squared dist(sample, tile bbox),
// so every term <= 1 (no overflow).
// Cull: max_px(min d) <= A + 2*HD, so one list with threshold
//   T = min(A + 2*HD, FARCUT) + RADIUS
// keeps all terms that matter; dropped terms each < exp(-256*0.06) ~ 2e-7,
// and pixels with d > FARCUT saturate to out = 1 within 7.5e-6.
// Far tile: A > FARCUT -> out = 1 immediately.

#define SIZE 512
#define RADIUS 0.06f
#define FARCUT 0.1217f          // 0.04 + ln(256)/256 + RADIUS
#define HB 0.00684932f          // 3.5/511         (pixel-center bbox half-extent)
#define HD 0.00968631f          // HB*sqrt(2)      (bbox half-diagonal)

__device__ __forceinline__ float clamp01(float x) {
    return fminf(fmaxf(x, 0.0f), 1.0f);
}
__device__ __forceinline__ float wave_min(float v) {
    #pragma unroll
    for (int m = 1; m < 64; m <<= 1) v = fminf(v, __shfl_xor(v, m));
    return v;
}

__global__ __launch_bounds__(64) void bezier_glyph_kernel(
        const float* __restrict__ cp,   // (8,4,2) control points
        float* __restrict__ out)        // (512*512)
{
    __shared__ float2 list[260];

    const int tid = threadIdx.x;        // == lane (single wave)
    const int b   = blockIdx.x;
    const int row_base = (b >> 6) << 3;
    const int col_base = (b & 63) << 3;
    const float inv = 1.0f / 511.0f;
    const float cx  = ((float)col_base + 3.5f) * inv;
    const float cy  = ((float)row_base + 3.5f) * inv;

    // ---- Stage 0: thread t evaluates samples 4t..4t+3 (one stroke, Horner) ----
    float sxv[4], syv[4], bb2v[4];
    {
        const int s = tid >> 3;                 // stroke of samples 4t..4t+3
        const float* p = cp + s * 8;
        const float x0 = clamp01(p[0]), y0 = clamp01(p[1]);
        const float x1 = clamp01(p[2]), y1 = clamp01(p[3]);
        const float x2 = clamp01(p[4]), y2 = clamp01(p[5]);
        const float x3 = clamp01(p[6]), y3 = clamp01(p[7]);
        // B(u) = x0 + c1 u + c2 u^2 + c3 u^3
        const float c1x = 3.0f * (x1 - x0);
        const float c2x = 3.0f * (x0 - 2.0f * x1 + x2);
        const float c3x = x3 - x0 + 3.0f * (x1 - x2);
        const float c1y = 3.0f * (y1 - y0);
        const float c2y = 3.0f * (y0 - 2.0f * y1 + y2);
        const float c3y = y3 - y0 + 3.0f * (y1 - y2);
        #pragma unroll
        for (int r = 0; r < 4; ++r) {
            const int j    = ((tid << 2) + r) & 31;
            const float u  = (float)j * (1.0f / 31.0f);
            const float sx = fmaf(fmaf(fmaf(c3x, u, c2x), u, c1x), u, x0);
            const float sy = fmaf(fmaf(fmaf(c3y, u, c2y), u, c1y), u, y0);
            sxv[r] = sx; syv[r] = sy;
            const float bx = fmaxf(fabsf(sx - cx) - HB, 0.0f);
            const float by = fmaxf(fabsf(sy - cy) - HB, 0.0f);
            bb2v[r] = fmaf(bx, bx, by * by);
        }
    }

    // ---- anchor: A = sqrt(min over all 256 samples of bb2) ----
    const float A = __builtin_amdgcn_sqrtf(wave_min(
        fminf(fminf(bb2v[0], bb2v[1]), fminf(bb2v[2], bb2v[3]))));

    const int row = row_base + (tid >> 3);
    const int col = col_base + (tid & 7);

    if (A > FARCUT) {                   // whole tile far: out == 1 (+-7.5e-6)
        out[row * SIZE + col] = 1.0f;
        return;
    }

    // ---- build the single culled list (ballot compaction, no atomics) ----
    const float T   = fminf(A + 2.0f * HD, FARCUT) + RADIUS + 1e-4f;
    const float Ts  = T * T;
    const unsigned long long lt = (1ull << tid) - 1ull;   // tid <= 63
    int n = 0;
    #pragma unroll
    for (int r = 0; r < 4; ++r) {
        const bool keep = (bb2v[r] <= Ts);
        const unsigned long long mk = __ballot(keep);
        if (keep)
            list[n + (int)__popcll(mk & lt)] = make_float2(sxv[r], syv[r]);
        n += (int)__popcll(mk);
    }
    if (tid < 4) list[n + tid] = make_float2(1e3f, 1e3f);  // pad -> exp2 -> 0
    __syncthreads();                    // single wave: just drains lgkmcnt

    // ---- fused pass: S = sum exp2(C*(A - d_k)) ----
    const float py = (float)row * inv;
    const float px = (float)col * inv;
    const float C  = 369.3299304675766f;   // 256 * log2(e)
    const float nC = -C;
    const float cA = C * A;
    float S = 0.0f;
    const int nr = (n + 3) & ~3;
    for (int k = 0; k < nr; k += 4) {
        const float2 a = list[k],     b2 = list[k + 1];
        const float2 c = list[k + 2], e  = list[k + 3];
        float dx, dy;
        dx = px - a.x;  dy = py - a.y;  const float qa = fmaf(dx, dx, dy * dy);
        dx = px - b2.x; dy = py - b2.y; const float qb = fmaf(dx, dx, dy * dy);
        dx = px - c.x;  dy = py - c.y;  const float qc = fmaf(dx, dx, dy * dy);
        dx = px - e.x;  dy = py - e.y;  const float qe = fmaf(dx, dx, dy * dy);
        S += __builtin_amdgcn_exp2f(fmaf(nC, __builtin_amdgcn_sqrtf(qa), cA))
           + __builtin_amdgcn_exp2f(fmaf(nC, __builtin_amdgcn_sqrtf(qb), cA))
           + __builtin_amdgcn_exp2f(fmaf(nC, __builtin_amdgcn_sqrtf(qc), cA))
           + __builtin_amdgcn_exp2f(fmaf(nC, __builtin_amdgcn_sqrtf(qe), cA));
    }

    // md = A - log2(S)/C  (exact logsumexp given the anchor)
    // S==0 (all terms underflow) -> log2 = -inf -> md = +inf -> out = 1: correct,
    // that requires every d_k > A + 0.34 -> true min > FARCUT.
    const float md = A - __builtin_amdgcn_logf(S) * (1.0f / C);
    const float K  = 288.53900817779268f;  // 200 * log2(e)
    out[row * SIZE + col] = __builtin_amdgcn_rcpf(
        1.0f + __builtin_amdgcn_exp2f((0.04f - md) * K));
}

extern "C" void kernel_launch(void* const* d_in, const int* in_sizes, int n_in,
                              void* d_out, int out_size, void* d_ws, size_t ws_size,
                              hipStream_t stream) {
    const float* cp = (const float*)d_in[0];   // control_points (8,4,2)
    float* out = (float*)d_out;                // pixel_grid recomputed in-kernel
    bezier_glyph_kernel<<<dim3(4096), dim3(64), 0, stream>>>(cp, out);
}